// Round 14
// baseline (563.512 us; speedup 1.0000x reference)
//
#include <hip/hip_runtime.h>

// ---------------- static problem dims ----------------
#define B_G   32
#define NXP   1024
#define NYP   512
#define NX_T  32768
#define NY_T  16384
#define E_T   65536
#define F_SZ  256
#define EMB_S 256
#define H_SZ  512
#define VOC   512

// d_out offsets (floats): (y3, ei, et, y_score, rel, embeds_out, a1, a2, a3)
static const long O_Y3  = 0;
static const long O_EI  = 4194304;
static const long O_ET  = 4325376;
static const long O_YS  = 4390912;
static const long O_REL = 12779520;
static const long O_EMB = 13238272;
static const long O_A1  = 21626880;
static const long O_A2  = 38404096;
static const long O_A3  = 55181312;

using bf16x8 = __attribute__((ext_vector_type(8))) __bf16;
using f32x4  = __attribute__((ext_vector_type(4))) float;

__device__ __forceinline__ ushort f2bf(float f) {
  union { float f; unsigned u; } v; v.f = f;
  return (ushort)((v.u + 0x7FFFu + ((v.u >> 16) & 1u)) >> 16);
}
__device__ __forceinline__ float bf2f(ushort s) {
  union { unsigned u; float f; } v; v.u = ((unsigned)s) << 16;
  return v.f;
}

__device__ __forceinline__ void g2l16(const ushort* g, ushort* l) {
  __builtin_amdgcn_global_load_lds(
      (const __attribute__((address_space(1))) void*)g,
      (__attribute__((address_space(3))) void*)l, 16, 0, 0);
}

// ---------------- generic MFMA GEMM ----------------
// BK=64, double-buffered LDS, counted-vmcnt raw-barrier pipeline (T4):
// prefetch stays in flight across barriers (never vmcnt(0) mid-loop),
// st-XOR LDS swizzle both-sides (T2, rule #21).
// R12/R13 lesson: BN is an OCCUPANCY knob (A-re-reads are L3-resident).
// BN=128: 64KB LDS -> 2 blocks/CU.  BN=64: 48KB LDS -> 3 blocks/CU.
struct GemmP {
  const ushort* A; const ushort* Bt;
  float* outF; ushort* outB; float* outF2; ushort* outB2;
  const float* addC; const float* bias; const float* rowScale;
  long sA, sBt, sOutF, sOutB, sAddC, sRS;
  int lda, ldb, ldoF, ldoB, ldoF2, ldoB2, ldC;
  int M, N, K, nSplit;
  float scale; int relu; int expf_;
};

template<int BN>
__global__ __launch_bounds__(256) void gemm_k(GemmP p) {
  constexpr int WGM = (BN == 128) ? 2 : 4;   // wave grid M
  constexpr int WGN = (BN == 128) ? 2 : 1;   // wave grid N
  constexpr int MT  = 128 / (16 * WGM);      // 4 or 2
  constexpr int NT  = BN / (16 * WGN);       // 4
  constexpr int NCB = (BN * 8) / 256;        // B chunks per thread (4 or 2)
  constexpr int ASZ = 128 * 64;              // per-buffer ushorts
  constexpr int BSZ = BN * 64;
  __shared__ __align__(16) ushort As[2 * ASZ];
  __shared__ __align__(16) ushort Bs[2 * BSZ];
  const int tid  = threadIdx.x;
  const int wave = tid >> 6, lane = tid & 63;

  // bijective XCD-panel swizzle: panel=(z,bm) chunks per XCD, bn fastest.
  // requires (gridDim.x*gridDim.z) % 8 == 0 (true for all call sites).
  const int GM = gridDim.x, GN = gridDim.y;
  const int L = blockIdx.x + GM * (blockIdx.y + GN * blockIdx.z);
  const int npan = GM * gridDim.z;
  const int q8 = npan >> 3;
  const int xcd = L & 7;
  const int i = L >> 3;
  const int bnn = i % GN;
  const int panel = xcd * q8 + i / GN;
  const int bmi = panel % GM;
  const int z = panel / GM;
  const int bm = bmi * 128, bn = bnn * BN;

  const ushort* A  = p.A  + (long)z * p.sA;
  const ushort* Bt = p.Bt + (long)z * p.sBt;

  const int wm = (wave / WGN) * (MT * 16);
  const int wn = (wave % WGN) * (NT * 16);
  const int lrow = lane & 15, hg = lane >> 4;
  const int e3 = lrow & 7;

  // staging: chunk c = row*8 + seg; LDS linear dest c*16B;
  // global source seg pre-swizzled: sg = seg ^ (row&7)  (rule #21)
  const ushort* pa[4]; int ca[4];
  const ushort* pb[NCB]; int cb[NCB];
#pragma unroll
  for (int q = 0; q < 4; ++q) {
    const int c = tid + 256 * q, row = c >> 3, sg = (c & 7) ^ (row & 7);
    pa[q] = A + (long)(bm + row) * p.lda + sg * 8;
    ca[q] = c * 8;
  }
#pragma unroll
  for (int q = 0; q < NCB; ++q) {
    const int c = tid + 256 * q, row = c >> 3, sg = (c & 7) ^ (row & 7);
    pb[q] = Bt + (long)(bn + row) * p.ldb + sg * 8;
    cb[q] = c * 8;
  }

  auto stage = [&](int t, int buf) {
    const int ke = t * 64;
#pragma unroll
    for (int q = 0; q < 4; ++q) g2l16(pa[q] + ke, &As[buf * ASZ + ca[q]]);
#pragma unroll
    for (int q = 0; q < NCB; ++q) g2l16(pb[q] + ke, &Bs[buf * BSZ + cb[q]]);
  };

  f32x4 acc[MT][NT];
#pragma unroll
  for (int m = 0; m < MT; ++m)
#pragma unroll
    for (int n = 0; n < NT; ++n) acc[m][n] = f32x4{0.f, 0.f, 0.f, 0.f};

  // pipeline: 2 tiles in flight; per-stage loads = 4 + NCB (8 or 6)
  stage(0, 0);
  stage(1, 1);
  const int nt = p.K >> 6;
  int cur = 0;
  for (int t = 0; t < nt; ++t) {
    // wait only for buf[cur]'s loads; keep the other stage in flight (T4)
    if (t + 1 < nt) {
      if constexpr (BN == 128) asm volatile("s_waitcnt vmcnt(8)" ::: "memory");
      else                     asm volatile("s_waitcnt vmcnt(6)" ::: "memory");
    } else {
      asm volatile("s_waitcnt vmcnt(0)" ::: "memory");
    }
    __builtin_amdgcn_s_barrier();          // all waves' buf[cur] chunks landed
    __builtin_amdgcn_sched_barrier(0);
    bf16x8 af[MT][2], bf[NT][2];
#pragma unroll
    for (int m = 0; m < MT; ++m) {
      const int rb = cur * ASZ + (wm + m * 16 + lrow) * 64;
#pragma unroll
      for (int kf = 0; kf < 2; ++kf)
        af[m][kf] = *(const bf16x8*)&As[rb + ((((kf << 2) | hg) ^ e3) << 3)];
    }
#pragma unroll
    for (int n = 0; n < NT; ++n) {
      const int rb = cur * BSZ + (wn + n * 16 + lrow) * 64;
#pragma unroll
      for (int kf = 0; kf < 2; ++kf)
        bf[n][kf] = *(const bf16x8*)&Bs[rb + ((((kf << 2) | hg) ^ e3) << 3)];
    }
    asm volatile("s_waitcnt lgkmcnt(0)" ::: "memory");  // my ds_reads retired
    __builtin_amdgcn_sched_barrier(0);                  // rule #18: pin MFMA below
    __builtin_amdgcn_s_barrier();          // all waves done reading buf[cur]
    __builtin_amdgcn_sched_barrier(0);
    if (t + 2 < nt) stage(t + 2, cur);     // refill just-freed buffer, stays in flight
    // swapped operands: D fast index = N, lane&15 = M
#pragma unroll
    for (int m = 0; m < MT; ++m)
#pragma unroll
      for (int n = 0; n < NT; ++n) {
        acc[m][n] = __builtin_amdgcn_mfma_f32_16x16x32_bf16(bf[n][0], af[m][0], acc[m][n], 0, 0, 0);
        acc[m][n] = __builtin_amdgcn_mfma_f32_16x16x32_bf16(bf[n][1], af[m][1], acc[m][n], 0, 0, 0);
      }
    cur ^= 1;
  }

  const int rr0 = hg * 4;
#pragma unroll
  for (int m = 0; m < MT; ++m) {
    const long mr = bm + wm + m * 16 + lrow;
    const float rs = p.rowScale ? p.rowScale[(long)z * p.sRS + mr] : 1.0f;
#pragma unroll
    for (int n = 0; n < NT; ++n) {
      const int nc = bn + wn + n * 16 + rr0;
      float vv[4];
#pragma unroll
      for (int j = 0; j < 4; ++j) vv[j] = acc[m][n][j] * p.scale;
      if (nc < p.nSplit) {
        if (p.expf_) {
#pragma unroll
          for (int j = 0; j < 4; ++j) vv[j] = __expf(vv[j]);
        }
#pragma unroll
        for (int j = 0; j < 4; ++j) vv[j] *= rs;
        if (p.addC) {
          float4 c4 = *(const float4*)&p.addC[(long)z * p.sAddC + mr * p.ldC + nc];
          vv[0] += c4.x; vv[1] += c4.y; vv[2] += c4.z; vv[3] += c4.w;
        }
        if (p.bias) {
          float4 b4 = *(const float4*)&p.bias[nc];
          vv[0] += b4.x; vv[1] += b4.y; vv[2] += b4.z; vv[3] += b4.w;
        }
        if (p.relu) {
#pragma unroll
          for (int j = 0; j < 4; ++j) vv[j] = fmaxf(vv[j], 0.f);
        }
        if (p.outF) {
          float4 o4 = make_float4(vv[0], vv[1], vv[2], vv[3]);
          *(float4*)&p.outF[(long)z * p.sOutF + mr * p.ldoF + nc] = o4;
        }
        if (p.outB) {
          ushort4 ob;
          ob.x = f2bf(vv[0]); ob.y = f2bf(vv[1]); ob.z = f2bf(vv[2]); ob.w = f2bf(vv[3]);
          *(ushort4*)&p.outB[(long)z * p.sOutB + mr * p.ldoB + nc] = ob;
        }
      } else {
        const int nc2 = nc - p.nSplit;
        if (p.outF2 && nc2 < p.ldoF2) {
          float4 o4 = make_float4(vv[0], vv[1], vv[2], vv[3]);
          *(float4*)&p.outF2[mr * (long)p.ldoF2 + nc2] = o4;
        }
        if (p.outB2 && nc2 < p.ldoB2) {
          ushort4 ob;
          ob.x = f2bf(vv[0]); ob.y = f2bf(vv[1]); ob.z = f2bf(vv[2]); ob.w = f2bf(vv[3]);
          *(ushort4*)&p.outB2[mr * (long)p.ldoB2 + nc2] = ob;
        }
      }
    }
  }
}

// ---------------- helper kernels ----------------
struct TD { const float* src; ushort* dst; int K; int N; int ldD; };
struct TDs { TD d[22]; };
// LDS-tiled transpose: dst[n*ldD + k] = bf16(src[k*N + n]); coalesced both ways
__global__ __launch_bounds__(256) void t32_k(TDs t) {
  TD d = t.d[blockIdx.z];
  const int k0 = blockIdx.x * 32, n0 = blockIdx.y * 32;
  if (k0 >= d.K || n0 >= d.N) return;
  __shared__ float tl[32][33];
  const int tx = threadIdx.x & 31, ty = threadIdx.x >> 5;
#pragma unroll
  for (int r = ty; r < 32; r += 8)
    if (k0 + r < d.K && n0 + tx < d.N)
      tl[r][tx] = d.src[(long)(k0 + r) * d.N + n0 + tx];
  __syncthreads();
#pragma unroll
  for (int r = ty; r < 32; r += 8)
    if (n0 + r < d.N && k0 + tx < d.K)
      d.dst[(long)(n0 + r) * d.ldD + k0 + tx] = f2bf(tl[tx][r]);
}

// fused: xb = bf16(x), xT[b][f][j] = bf16(x[b*1024+j][f]) — reads x once
__global__ __launch_bounds__(256) void prepx_k(const float* x, ushort* xb, ushort* xT) {
  __shared__ float t[32][33];
  int b = blockIdx.z;
  int j0 = blockIdx.x * 32, f0 = blockIdx.y * 32;
  int tx = threadIdx.x & 31, ty = threadIdx.x >> 5;
#pragma unroll
  for (int r = ty; r < 32; r += 8) {
    float v = x[((long)b * NXP + j0 + r) * F_SZ + f0 + tx];
    t[r][tx] = v;
    xb[((long)b * NXP + j0 + r) * F_SZ + f0 + tx] = f2bf(v);
  }
  __syncthreads();
#pragma unroll
  for (int r = ty; r < 32; r += 8)
    xT[((long)b * F_SZ + f0 + r) * NXP + j0 + tx] = f2bf(t[tx][r]);
}

__global__ void gather_k(const float* emb, const int* tgt_y, ushort* y0b) {
  long i = (long)blockIdx.x * 256 + threadIdx.x;
  int n = (int)(i >> 6), c = (int)(i & 63) * 4;
  int row = tgt_y[n];
  float4 v = *(const float4*)&emb[(long)row * EMB_S + c];
  ushort4 o; o.x = f2bf(v.x); o.y = f2bf(v.y); o.z = f2bf(v.z); o.w = f2bf(v.w);
  *(ushort4*)&y0b[(long)n * EMB_S + c] = o;
}

// row sums of exp-scores: 2 rows/block, 16B loads; alpha f32 -> out, inv -> ws
__global__ __launch_bounds__(256) void rowsum_k(const ushort* E, float* aF, float* inv) {
  __shared__ float red[2][2];
  const int tid = threadIdx.x;
  const int half = tid >> 7, t = tid & 127;
  const long row = (long)blockIdx.x * 2 + half;
  const ushort* e = E + row * 1024;
  int4 u = *(const int4*)&e[t * 8];
  const ushort* us = (const ushort*)&u;
  float v[8]; float s = 0.f;
#pragma unroll
  for (int j = 0; j < 8; ++j) { v[j] = bf2f(us[j]); s += v[j]; }
  const int lane = t & 63, wv = t >> 6;
#pragma unroll
  for (int o = 32; o; o >>= 1) s += __shfl_xor(s, o, 64);
  if (lane == 0) red[half][wv] = s;
  __syncthreads();
  float iv = 1.0f / (red[half][0] + red[half][1]);
  float* d = &aF[row * 1024 + t * 8];
  float4 a0 = make_float4(v[0] * iv, v[1] * iv, v[2] * iv, v[3] * iv);
  float4 a1 = make_float4(v[4] * iv, v[5] * iv, v[6] * iv, v[7] * iv);
  *(float4*)&d[0] = a0;
  *(float4*)&d[4] = a1;
  if (t == 0) inv[row] = iv;
}

// ---------------- CSR build ----------------
__global__ void deg_k(const int* ei, int* cnt) {
  int e = blockIdx.x * 256 + threadIdx.x;
  atomicAdd(&cnt[ei[E_T + e]], 1);
}

__global__ __launch_bounds__(256) void scan_k(const int* cnt, int* ofs, int* cur) {
  __shared__ int sh[256];
  const int t = threadIdx.x;
  int s = 0;
  for (int i = 0; i < 64; ++i) s += cnt[t * 64 + i];
  sh[t] = s; __syncthreads();
  for (int d = 1; d < 256; d <<= 1) {
    int v = (t >= d) ? sh[t - d] : 0;
    __syncthreads();
    sh[t] += v;
    __syncthreads();
  }
  int run = sh[t] - s;
  for (int i = 0; i < 64; ++i) {
    int v = cnt[t * 64 + i];
    ofs[t * 64 + i] = run; cur[t * 64 + i] = run;
    run += v;
  }
  if (t == 255) ofs[16384] = run;
}

__global__ void fill_k(const int* ei, const int* et, int* cur, ushort* adj) {
  int e = blockIdx.x * 256 + threadIdx.x;
  int d = ei[E_T + e];
  int pos = atomicAdd(&cur[d], 1);
  adj[pos] = (ushort)(ei[e] | (et[e] << 14));
}

// ya[dst][t*ni + c..c+7] = sum over CSR edges of type t (16B loads, NAMED accums
// with static indexing only — rule #20: runtime-indexed arrays spill to scratch)
__global__ __launch_bounds__(256) void gather_y_k(const ushort* y, const ushort* adj,
                                                  const int* ofs, ushort* Abuf,
                                                  int ni, int ldA) {
  const int tpr = ni >> 3;                      // threads per row (32 or 64)
  const int r = blockIdx.x * (256 / tpr) + threadIdx.x / tpr;
  const int c = (threadIdx.x % tpr) * 8;
  const int s0 = ofs[r], s1 = ofs[r + 1];
  float A0[8], A1[8], A2[8], A3[8];
#pragma unroll
  for (int j = 0; j < 8; ++j) { A0[j] = 0.f; A1[j] = 0.f; A2[j] = 0.f; A3[j] = 0.f; }
  for (int i = s0; i < s1; ++i) {
    const unsigned ad = adj[i];
    const int src = ad & 0x3FFF, t = ad >> 14;
    int4 u = *(const int4*)&y[(long)src * ni + c];
    const ushort* us = (const ushort*)&u;
    if (t == 0) {
#pragma unroll
      for (int j = 0; j < 8; ++j) A0[j] += bf2f(us[j]);
    } else if (t == 1) {
#pragma unroll
      for (int j = 0; j < 8; ++j) A1[j] += bf2f(us[j]);
    } else if (t == 2) {
#pragma unroll
      for (int j = 0; j < 8; ++j) A2[j] += bf2f(us[j]);
    } else {
#pragma unroll
      for (int j = 0; j < 8; ++j) A3[j] += bf2f(us[j]);
    }
  }
  ushort* d = &Abuf[(long)r * ldA + c];
  int4 o; ushort* os = (ushort*)&o;
#pragma unroll
  for (int j = 0; j < 8; ++j) os[j] = f2bf(A0[j]);
  *(int4*)&d[0] = o;
#pragma unroll
  for (int j = 0; j < 8; ++j) os[j] = f2bf(A1[j]);
  *(int4*)&d[ni] = o;
#pragma unroll
  for (int j = 0; j < 8; ++j) os[j] = f2bf(A2[j]);
  *(int4*)&d[2 * ni] = o;
#pragma unroll
  for (int j = 0; j < 8; ++j) os[j] = f2bf(A3[j]);
  *(int4*)&d[3 * ni] = o;
}

// merged: rel scores + index copies (one dispatch)
__global__ void erelic_k(const float* Gbuf, const int* ei, const int* et,
                         const float* bg, float* outR, float* oEI, float* oET) {
  const long nrel = (long)E_T * 7;
  long idx = (long)blockIdx.x * 256 + threadIdx.x;
  if (idx < nrel) {
    int e = (int)(idx / 7), r = (int)(idx - (long)e * 7);
    outR[idx] = Gbuf[(long)ei[e] * 16 + r] + Gbuf[(long)ei[E_T + e] * 16 + 7 + r] + bg[r];
  } else {
    long j = idx - nrel;
    if (j < 2 * E_T) oEI[j] = (float)ei[j];
    else if (j < 3 * E_T) oET[j - 2 * E_T] = (float)et[j - 2 * E_T];
  }
}

// ---------------- host side ----------------
static GemmP mkp(const ushort* A, long sA, int lda,
                 const ushort* Bt, long sBt, int ldb,
                 int M, int N, int K,
                 float* outF, long sOF, int ldoF,
                 ushort* outB, long sOB, int ldoB,
                 const float* addC, long sC, int ldC,
                 const float* bias, float scale, int relu,
                 int expf_, const float* rowScale, long sRS) {
  GemmP p{};
  p.A = A; p.Bt = Bt; p.outF = outF; p.outB = outB; p.outF2 = nullptr; p.outB2 = nullptr;
  p.addC = addC; p.bias = bias; p.rowScale = rowScale;
  p.sA = sA; p.sBt = sBt; p.sOutF = sOF; p.sOutB = sOB; p.sAddC = sC; p.sRS = sRS;
  p.lda = lda; p.ldb = ldb; p.ldoF = ldoF; p.ldoB = ldoB; p.ldoF2 = 0; p.ldoB2 = 0; p.ldC = ldC;
  p.M = M; p.N = N; p.K = K; p.nSplit = 1 << 30;
  p.scale = scale; p.relu = relu; p.expf_ = expf_;
  return p;
}

static void gemm128(hipStream_t st, const GemmP& p, int Z) {
  dim3 grid(p.M / 128, p.N / 128, Z);
  hipLaunchKernelGGL(gemm_k<128>, grid, dim3(256), 0, st, p);
}
static void gemm64(hipStream_t st, const GemmP& p, int Z) {
  dim3 grid(p.M / 128, p.N / 64, Z);
  hipLaunchKernelGGL(gemm_k<64>, grid, dim3(256), 0, st, p);
}

extern "C" void kernel_launch(void* const* d_in, const int* in_sizes, int n_in,
                              void* d_out_, int out_size, void* d_ws, size_t ws_size,
                              hipStream_t stream) {
  const float* x     = (const float*)d_in[0];
  const int*   tgt_y = (const int*)d_in[1];
  const int*   ei    = (const int*)d_in[2];
  const int*   et    = (const int*)d_in[3];
  const float* emb   = (const float*)d_in[6];
  const float* Wz    = (const float*)d_in[7];
  const float* bz    = (const float*)d_in[8];
  const float* Wg    = (const float*)d_in[9];
  const float* bg    = (const float*)d_in[10];
  const float* We[3] = {(const float*)d_in[11], (const float*)d_in[15], (const float*)d_in[19]};
  const float* Wq[3] = {(const float*)d_in[12], (const float*)d_in[16], (const float*)d_in[20]};
  const float* Wc[3] = {(const float*)d_in[13], (const float*)d_in[17], (const float*)d_in[21]};
  const float* bb[3] = {(const float*)d_in[14], (const float*)d_in[18], (const float*)d_in[22]};
  float* out = (float*)d_out_;

  // ---- workspace layout (ushort units) ----
  ushort* wsu    = (ushort*)d_ws;
  ushort* WzG    = wsu + 0;          // [640][256]: Wz 0-511, Wg1T 512-518, Wg2T 519-525, pad->639
  ushort* WzQ1   = wsu + 163840;     // [768][256]: Wz 0-511, Wq1T 512-767
  ushort* WB0    = wsu + 360448;     // [512][1280]
  ushort* WB1    = wsu + 1015808;    // [512][2304]
  ushort* WB2    = wsu + 2195456;    // [256][2304]
  ushort* WqT2   = wsu + 2785280;    // [256][512]
  ushort* WqT3   = wsu + 2916352;    // [256][512]
  ushort* xb     = wsu + 3047424;    // bf16 x [32768,256]
  ushort* xTb    = wsu + 11436032;   // bf16 xT [32][256][1024]
  ushort* qbuf   = wsu + 19824640;   // bf16 q [16384,256]
  ushort* ybuf   = wsu + 24018944;   // bf16 y [16384,<=512]
  ushort* Abuf   = wsu + 32407552;   // bf16 [16384][<=2304]
  ushort* scoreb = wsu + 70156288;   // bf16 exp-scores [16384,1024]
  float*  Gbuf   = (float*)(wsu + 86933504);  // f32 [16384,16]
  float*  inv    = (float*)(wsu + 91127808);  // 16384 f
  float*  bcat   = (float*)(wsu + 91160576);  // 768 f
  int*    cnt    = (int*)(wsu + 91162112);    // 16384
  int*    ofs    = (int*)(wsu + 91194880);    // 16385
  int*    cur    = (int*)(wsu + 91227712);    // 16384
  ushort* adj    = wsu + 91260480;            // 65536

  ushort* GgT  = WzG + 512 * 256;
  ushort* Wq1T = WzQ1 + 512 * 256;
  ushort* WB[3]  = {WB0, WB1, WB2};
  const int ni_l[3] = {256, 512, 512}, no_l[3] = {512, 512, 256};
  const int ldA_l[3] = {1280, 2304, 2304};

  // ---- small prep ----
  hipMemcpyAsync(bcat, bz, 512 * sizeof(float), hipMemcpyDeviceToDevice, stream);
  hipMemsetAsync(bcat + 512, 0, 256 * sizeof(float), stream);
  hipMemsetAsync(GgT + 14 * 256, 0, (128 - 14) * 256 * sizeof(ushort), stream);
  hipMemsetAsync(cnt, 0, 16384 * sizeof(int), stream);

  // ---- weight transposes (22 slabs, LDS-tiled) ----
  TDs td; int di = 0;
  td.d[di++] = {Wz, WzG, 256, 512, 256};
  td.d[di++] = {Wz, WzQ1, 256, 512, 256};
  td.d[di++] = {Wg, GgT, 256, 7, 256};
  td.d[di++] = {Wg + 256 * 7, GgT + 7 * 256, 256, 7, 256};
  td.d[di++] = {Wq[0], Wq1T, 256, 256, 256};
  for (int l = 0; l < 3; ++l) {
    const int ni = ni_l[l], no = no_l[l], ldA = ldA_l[l];
    for (int t = 0; t < 4; ++t)
      td.d[di++] = {We[l] + (long)t * ni * no, WB[l] + (long)t * ni, ni, no, ldA};
    td.d[di++] = {Wc[l], WB[l] + (long)4 * ni, 256, no, ldA};
    if (l > 0) td.d[di++] = {Wq[l], (l == 1) ? WqT2 : WqT3, ni, 256, ni};
  }
  hipLaunchKernelGGL(t32_k, dim3(16, 16, 22), dim3(256), 0, stream, td);

  hipLaunchKernelGGL(prepx_k, dim3(32, 8, 32), dim3(256), 0, stream, x, xb, xTb);
  hipLaunchKernelGGL(gather_k, dim3(4096), dim3(256), 0, stream, emb, tgt_y, ybuf);

  // ---- CSR build ----
  hipLaunchKernelGGL(deg_k, dim3(256), dim3(256), 0, stream, ei, cnt);
  hipLaunchKernelGGL(scan_k, dim3(1), dim3(256), 0, stream, cnt, ofs, cur);
  hipLaunchKernelGGL(fill_k, dim3(256), dim3(256), 0, stream, ei, et, cur, adj);

  // ---- merged: [embeds_out | q1] = y0 @ [Wz | Wq1]  (BN=64: 3 blocks/CU) ----
  {
    GemmP p = mkp(ybuf, 0, 256, WzQ1, 0, 256, NY_T, 768, 256,
                  out + O_EMB, 0, 512, nullptr, 0, 0,
                  nullptr, 0, 0, bcat, 1.0f, 0, 0, nullptr, 0);
    p.nSplit = 512; p.outB2 = qbuf; p.ldoB2 = 256;
    gemm64(stream, p, 1);
  }

  float* alphaO[3] = {out + O_A1, out + O_A2, out + O_A3};
  ushort* WqTn[3] = {nullptr, WqT2, WqT3};

  for (int l = 0; l < 3; ++l) {
    const int ni = ni_l[l], no = no_l[l], ldA = ldA_l[l];
    if (l > 0) {   // q = y @ Wq (BN=64)
      GemmP p = mkp(ybuf, 0, ni, WqTn[l], 0, ni, NY_T, 256, ni,
                    nullptr, 0, 0, qbuf, 0, 256,
                    nullptr, 0, 0, nullptr, 1.0f, 0, 0, nullptr, 0);
      gemm64(stream, p, 1);
    }
    // ya: CSR gather of y into Abuf[:, 0..4ni)
    hipLaunchKernelGGL(gather_y_k, dim3(NY_T / (256 / (ni >> 3))), dim3(256), 0, stream,
                       ybuf, adj, ofs, Abuf, ni, ldA);
    // e = exp(q @ x^T / 16) (batched, BN=128) -> scoreb bf16
    {
      GemmP p = mkp(qbuf, (long)512 * 256, 256, xb, (long)1024 * 256, 256,
                    512, 1024, 256, nullptr, 0, 0, scoreb, (long)512 * 1024, 1024,
                    nullptr, 0, 0, nullptr, 0.0625f, 0, 1, nullptr, 0);
      gemm128(stream, p, 32);
    }
    // row sums: alpha f32 -> out, inv -> ws
    hipLaunchKernelGGL(rowsum_k, dim3(8192), dim3(256), 0, stream, scoreb, alphaO[l], inv);
    // ctx = (e @ x) * inv[row] (batched, BN=64) -> Abuf[:, 4ni..)
    {
      GemmP p = mkp(scoreb, (long)512 * 1024, 1024, xTb, (long)256 * 1024, 1024,
                    512, 256, 1024, nullptr, 0, 0, Abuf + 4 * ni, (long)512 * ldA, ldA,
                    nullptr, 0, 0, nullptr, 1.0f, 0, 0, inv, 512);
      gemm64(stream, p, 32);
    }
    // y_next = relu([ya|ctx] @ WB^T + b)  (BN=64: 3 blocks/CU, 1024+ blocks)
    {
      GemmP p = mkp(Abuf, 0, ldA, WB[l], 0, ldA, NY_T, no, ldA,
                    (l == 2) ? out + O_Y3 : nullptr, 0, no, ybuf, 0, no,
                    nullptr, 0, 0, bb[l], 1.0f, 1, 0, nullptr, 0);
      gemm64(stream, p, 1);
    }
  }

  // ---- merged: [y_score | G] = y3 @ [Wz | Wg1 | Wg2 | pad]  (BN=64) ----
  {
    GemmP p = mkp(ybuf, 0, 256, WzG, 0, 256, NY_T, 640, 256,
                  out + O_YS, 0, 512, nullptr, 0, 0,
                  nullptr, 0, 0, bcat, 1.0f, 0, 0, nullptr, 0);
    p.nSplit = 512; p.outF2 = Gbuf; p.ldoF2 = 16;
    gemm64(stream, p, 1);
  }
  hipLaunchKernelGGL(erelic_k, dim3(2560), dim3(256), 0, stream,
                     Gbuf, ei, et, bg, out + O_REL, out + O_EI, out + O_ET);
}

// Round 16
// 498.323 us; speedup vs baseline: 1.1308x; 1.1308x over previous
//
#include <hip/hip_runtime.h>

// ---------------- static problem dims ----------------
#define B_G   32
#define NXP   1024
#define NYP   512
#define NX_T  32768
#define NY_T  16384
#define E_T   65536
#define F_SZ  256
#define EMB_S 256
#define H_SZ  512
#define VOC   512

// d_out offsets (floats): (y3, ei, et, y_score, rel, embeds_out, a1, a2, a3)
static const long O_Y3  = 0;
static const long O_EI  = 4194304;
static const long O_ET  = 4325376;
static const long O_YS  = 4390912;
static const long O_REL = 12779520;
static const long O_EMB = 13238272;
static const long O_A1  = 21626880;
static const long O_A2  = 38404096;
static const long O_A3  = 55181312;

using bf16x8 = __attribute__((ext_vector_type(8))) __bf16;
using f32x4  = __attribute__((ext_vector_type(4))) float;

__device__ __forceinline__ ushort f2bf(float f) {
  union { float f; unsigned u; } v; v.f = f;
  return (ushort)((v.u + 0x7FFFu + ((v.u >> 16) & 1u)) >> 16);
}
__device__ __forceinline__ float bf2f(ushort s) {
  union { unsigned u; float f; } v; v.u = ((unsigned)s) << 16;
  return v.f;
}

__device__ __forceinline__ void g2l16(const ushort* g, ushort* l) {
  __builtin_amdgcn_global_load_lds(
      (const __attribute__((address_space(1))) void*)g,
      (__attribute__((address_space(3))) void*)l, 16, 0, 0);
}

// non-temporal 16B f32 store via NATIVE vector type (float4 struct is rejected
// by __builtin_nontemporal_store — R15 compile-fail lesson)
__device__ __forceinline__ void nt_store4(float* p, float a, float b, float c, float d) {
  f32x4 v = {a, b, c, d};
  __builtin_nontemporal_store(v, (f32x4*)p);
}
__device__ __forceinline__ void nt_store1(float* p, float v) {
  __builtin_nontemporal_store(v, p);
}

// ---------------- generic MFMA GEMM ----------------
// BK=64, double-buffered LDS, counted-vmcnt raw-barrier pipeline (T4):
// prefetch stays in flight across barriers (never vmcnt(0) mid-loop),
// st-XOR LDS swizzle both-sides (T2, rule #21).
// BN map (R12/R13/R14): BN is an OCCUPANCY knob; BN=64 only where BN=128
// would leave <2 blocks/CU (N=256 shapes). A-re-reads are L3-resident.
struct GemmP {
  const ushort* A; const ushort* Bt;
  float* outF; ushort* outB; float* outF2; ushort* outB2;
  const float* addC; const float* bias; const float* rowScale;
  long sA, sBt, sOutF, sOutB, sAddC, sRS;
  int lda, ldb, ldoF, ldoB, ldoF2, ldoB2, ldC;
  int M, N, K, nSplit;
  float scale; int relu; int expf_;
};

template<int BN>
__global__ __launch_bounds__(256) void gemm_k(GemmP p) {
  constexpr int WGM = (BN == 128) ? 2 : 4;   // wave grid M
  constexpr int WGN = (BN == 128) ? 2 : 1;   // wave grid N
  constexpr int MT  = 128 / (16 * WGM);      // 4 or 2
  constexpr int NT  = BN / (16 * WGN);       // 4
  constexpr int NCB = (BN * 8) / 256;        // B chunks per thread (4 or 2)
  constexpr int ASZ = 128 * 64;              // per-buffer ushorts
  constexpr int BSZ = BN * 64;
  __shared__ __align__(16) ushort As[2 * ASZ];
  __shared__ __align__(16) ushort Bs[2 * BSZ];
  const int tid  = threadIdx.x;
  const int wave = tid >> 6, lane = tid & 63;

  // bijective XCD-panel swizzle: panel=(z,bm) chunks per XCD, bn fastest.
  // requires (gridDim.x*gridDim.z) % 8 == 0 (true for all call sites).
  const int GM = gridDim.x, GN = gridDim.y;
  const int L = blockIdx.x + GM * (blockIdx.y + GN * blockIdx.z);
  const int npan = GM * gridDim.z;
  const int q8 = npan >> 3;
  const int xcd = L & 7;
  const int i = L >> 3;
  const int bnn = i % GN;
  const int panel = xcd * q8 + i / GN;
  const int bmi = panel % GM;
  const int z = panel / GM;
  const int bm = bmi * 128, bn = bnn * BN;

  const ushort* A  = p.A  + (long)z * p.sA;
  const ushort* Bt = p.Bt + (long)z * p.sBt;

  const int wm = (wave / WGN) * (MT * 16);
  const int wn = (wave % WGN) * (NT * 16);
  const int lrow = lane & 15, hg = lane >> 4;
  const int e3 = lrow & 7;

  // staging: chunk c = row*8 + seg; LDS linear dest c*16B;
  // global source seg pre-swizzled: sg = seg ^ (row&7)  (rule #21)
  const ushort* pa[4]; int ca[4];
  const ushort* pb[NCB]; int cb[NCB];
#pragma unroll
  for (int q = 0; q < 4; ++q) {
    const int c = tid + 256 * q, row = c >> 3, sg = (c & 7) ^ (row & 7);
    pa[q] = A + (long)(bm + row) * p.lda + sg * 8;
    ca[q] = c * 8;
  }
#pragma unroll
  for (int q = 0; q < NCB; ++q) {
    const int c = tid + 256 * q, row = c >> 3, sg = (c & 7) ^ (row & 7);
    pb[q] = Bt + (long)(bn + row) * p.ldb + sg * 8;
    cb[q] = c * 8;
  }

  auto stage = [&](int t, int buf) {
    const int ke = t * 64;
#pragma unroll
    for (int q = 0; q < 4; ++q) g2l16(pa[q] + ke, &As[buf * ASZ + ca[q]]);
#pragma unroll
    for (int q = 0; q < NCB; ++q) g2l16(pb[q] + ke, &Bs[buf * BSZ + cb[q]]);
  };

  f32x4 acc[MT][NT];
#pragma unroll
  for (int m = 0; m < MT; ++m)
#pragma unroll
    for (int n = 0; n < NT; ++n) acc[m][n] = f32x4{0.f, 0.f, 0.f, 0.f};

  // pipeline: 2 tiles in flight; per-stage loads = 4 + NCB (8 or 6)
  stage(0, 0);
  stage(1, 1);
  const int nt = p.K >> 6;
  int cur = 0;
  for (int t = 0; t < nt; ++t) {
    // wait only for buf[cur]'s loads; keep the other stage in flight (T4)
    if (t + 1 < nt) {
      if constexpr (BN == 128) asm volatile("s_waitcnt vmcnt(8)" ::: "memory");
      else                     asm volatile("s_waitcnt vmcnt(6)" ::: "memory");
    } else {
      asm volatile("s_waitcnt vmcnt(0)" ::: "memory");
    }
    __builtin_amdgcn_s_barrier();          // all waves' buf[cur] chunks landed
    __builtin_amdgcn_sched_barrier(0);
    bf16x8 af[MT][2], bf[NT][2];
#pragma unroll
    for (int m = 0; m < MT; ++m) {
      const int rb = cur * ASZ + (wm + m * 16 + lrow) * 64;
#pragma unroll
      for (int kf = 0; kf < 2; ++kf)
        af[m][kf] = *(const bf16x8*)&As[rb + ((((kf << 2) | hg) ^ e3) << 3)];
    }
#pragma unroll
    for (int n = 0; n < NT; ++n) {
      const int rb = cur * BSZ + (wn + n * 16 + lrow) * 64;
#pragma unroll
      for (int kf = 0; kf < 2; ++kf)
        bf[n][kf] = *(const bf16x8*)&Bs[rb + ((((kf << 2) | hg) ^ e3) << 3)];
    }
    asm volatile("s_waitcnt lgkmcnt(0)" ::: "memory");  // my ds_reads retired
    __builtin_amdgcn_sched_barrier(0);                  // rule #18: pin MFMA below
    __builtin_amdgcn_s_barrier();          // all waves done reading buf[cur]
    __builtin_amdgcn_sched_barrier(0);
    if (t + 2 < nt) stage(t + 2, cur);     // refill just-freed buffer, stays in flight
    // swapped operands: D fast index = N, lane&15 = M
#pragma unroll
    for (int m = 0; m < MT; ++m)
#pragma unroll
      for (int n = 0; n < NT; ++n) {
        acc[m][n] = __builtin_amdgcn_mfma_f32_16x16x32_bf16(bf[n][0], af[m][0], acc[m][n], 0, 0, 0);
        acc[m][n] = __builtin_amdgcn_mfma_f32_16x16x32_bf16(bf[n][1], af[m][1], acc[m][n], 0, 0, 0);
      }
    cur ^= 1;
  }

  const int rr0 = hg * 4;
#pragma unroll
  for (int m = 0; m < MT; ++m) {
    const long mr = bm + wm + m * 16 + lrow;
    const float rs = p.rowScale ? p.rowScale[(long)z * p.sRS + mr] : 1.0f;
#pragma unroll
    for (int n = 0; n < NT; ++n) {
      const int nc = bn + wn + n * 16 + rr0;
      float vv[4];
#pragma unroll
      for (int j = 0; j < 4; ++j) vv[j] = acc[m][n][j] * p.scale;
      if (nc < p.nSplit) {
        if (p.expf_) {
#pragma unroll
          for (int j = 0; j < 4; ++j) vv[j] = __expf(vv[j]);
        }
#pragma unroll
        for (int j = 0; j < 4; ++j) vv[j] *= rs;
        if (p.addC) {
          float4 c4 = *(const float4*)&p.addC[(long)z * p.sAddC + mr * p.ldC + nc];
          vv[0] += c4.x; vv[1] += c4.y; vv[2] += c4.z; vv[3] += c4.w;
        }
        if (p.bias) {
          float4 b4 = *(const float4*)&p.bias[nc];
          vv[0] += b4.x; vv[1] += b4.y; vv[2] += b4.z; vv[3] += b4.w;
        }
        if (p.relu) {
#pragma unroll
          for (int j = 0; j < 4; ++j) vv[j] = fmaxf(vv[j], 0.f);
        }
        if (p.outF)
          nt_store4(&p.outF[(long)z * p.sOutF + mr * p.ldoF + nc], vv[0], vv[1], vv[2], vv[3]);
        if (p.outB) {
          ushort4 ob;
          ob.x = f2bf(vv[0]); ob.y = f2bf(vv[1]); ob.z = f2bf(vv[2]); ob.w = f2bf(vv[3]);
          *(ushort4*)&p.outB[(long)z * p.sOutB + mr * p.ldoB + nc] = ob;
        }
      } else {
        const int nc2 = nc - p.nSplit;
        if (p.outF2 && nc2 < p.ldoF2)
          nt_store4(&p.outF2[mr * (long)p.ldoF2 + nc2], vv[0], vv[1], vv[2], vv[3]);
        if (p.outB2 && nc2 < p.ldoB2) {
          ushort4 ob;
          ob.x = f2bf(vv[0]); ob.y = f2bf(vv[1]); ob.z = f2bf(vv[2]); ob.w = f2bf(vv[3]);
          *(ushort4*)&p.outB2[mr * (long)p.ldoB2 + nc2] = ob;
        }
      }
    }
  }
}

// ---------------- helper kernels ----------------
struct TD { const float* src; ushort* dst; int K; int N; int ldD; };
struct TDs { TD d[22]; };
// LDS-tiled transpose: dst[n*ldD + k] = bf16(src[k*N + n]); coalesced both ways
__global__ __launch_bounds__(256) void t32_k(TDs t) {
  TD d = t.d[blockIdx.z];
  const int k0 = blockIdx.x * 32, n0 = blockIdx.y * 32;
  if (k0 >= d.K || n0 >= d.N) return;
  __shared__ float tl[32][33];
  const int tx = threadIdx.x & 31, ty = threadIdx.x >> 5;
#pragma unroll
  for (int r = ty; r < 32; r += 8)
    if (k0 + r < d.K && n0 + tx < d.N)
      tl[r][tx] = d.src[(long)(k0 + r) * d.N + n0 + tx];
  __syncthreads();
#pragma unroll
  for (int r = ty; r < 32; r += 8)
    if (n0 + r < d.N && k0 + tx < d.K)
      d.dst[(long)(n0 + r) * d.ldD + k0 + tx] = f2bf(tl[tx][r]);
}

// fused: xb = bf16(x), xT[b][f][j] = bf16(x[b*1024+j][f]) — reads x once
__global__ __launch_bounds__(256) void prepx_k(const float* x, ushort* xb, ushort* xT) {
  __shared__ float t[32][33];
  int b = blockIdx.z;
  int j0 = blockIdx.x * 32, f0 = blockIdx.y * 32;
  int tx = threadIdx.x & 31, ty = threadIdx.x >> 5;
#pragma unroll
  for (int r = ty; r < 32; r += 8) {
    float v = x[((long)b * NXP + j0 + r) * F_SZ + f0 + tx];
    t[r][tx] = v;
    xb[((long)b * NXP + j0 + r) * F_SZ + f0 + tx] = f2bf(v);
  }
  __syncthreads();
#pragma unroll
  for (int r = ty; r < 32; r += 8)
    xT[((long)b * F_SZ + f0 + r) * NXP + j0 + tx] = f2bf(t[tx][r]);
}

__global__ void gather_k(const float* emb, const int* tgt_y, ushort* y0b) {
  long i = (long)blockIdx.x * 256 + threadIdx.x;
  int n = (int)(i >> 6), c = (int)(i & 63) * 4;
  int row = tgt_y[n];
  float4 v = *(const float4*)&emb[(long)row * EMB_S + c];
  ushort4 o; o.x = f2bf(v.x); o.y = f2bf(v.y); o.z = f2bf(v.z); o.w = f2bf(v.w);
  *(ushort4*)&y0b[(long)n * EMB_S + c] = o;
}

// row sums of exp-scores: 2 rows/block, 16B loads; alpha f32 (nt) -> out, inv -> ws
__global__ __launch_bounds__(256) void rowsum_k(const ushort* E, float* aF, float* inv) {
  __shared__ float red[2][2];
  const int tid = threadIdx.x;
  const int half = tid >> 7, t = tid & 127;
  const long row = (long)blockIdx.x * 2 + half;
  const ushort* e = E + row * 1024;
  int4 u = *(const int4*)&e[t * 8];
  const ushort* us = (const ushort*)&u;
  float v[8]; float s = 0.f;
#pragma unroll
  for (int j = 0; j < 8; ++j) { v[j] = bf2f(us[j]); s += v[j]; }
  const int lane = t & 63, wv = t >> 6;
#pragma unroll
  for (int o = 32; o; o >>= 1) s += __shfl_xor(s, o, 64);
  if (lane == 0) red[half][wv] = s;
  __syncthreads();
  float iv = 1.0f / (red[half][0] + red[half][1]);
  float* d = &aF[row * 1024 + t * 8];
  nt_store4(&d[0], v[0] * iv, v[1] * iv, v[2] * iv, v[3] * iv);
  nt_store4(&d[4], v[4] * iv, v[5] * iv, v[6] * iv, v[7] * iv);
  if (t == 0) inv[row] = iv;
}

// ---------------- CSR build ----------------
__global__ void deg_k(const int* ei, int* cnt) {
  int e = blockIdx.x * 256 + threadIdx.x;
  atomicAdd(&cnt[ei[E_T + e]], 1);
}

__global__ __launch_bounds__(256) void scan_k(const int* cnt, int* ofs, int* cur) {
  __shared__ int sh[256];
  const int t = threadIdx.x;
  int s = 0;
  for (int i = 0; i < 64; ++i) s += cnt[t * 64 + i];
  sh[t] = s; __syncthreads();
  for (int d = 1; d < 256; d <<= 1) {
    int v = (t >= d) ? sh[t - d] : 0;
    __syncthreads();
    sh[t] += v;
    __syncthreads();
  }
  int run = sh[t] - s;
  for (int i = 0; i < 64; ++i) {
    int v = cnt[t * 64 + i];
    ofs[t * 64 + i] = run; cur[t * 64 + i] = run;
    run += v;
  }
  if (t == 255) ofs[16384] = run;
}

__global__ void fill_k(const int* ei, const int* et, int* cur, ushort* adj) {
  int e = blockIdx.x * 256 + threadIdx.x;
  int d = ei[E_T + e];
  int pos = atomicAdd(&cur[d], 1);
  adj[pos] = (ushort)(ei[e] | (et[e] << 14));
}

// ya[dst][t*ni + c..c+7] = sum over CSR edges of type t (16B loads, NAMED accums
// with static indexing only — rule #20: runtime-indexed arrays spill to scratch)
__global__ __launch_bounds__(256) void gather_y_k(const ushort* y, const ushort* adj,
                                                  const int* ofs, ushort* Abuf,
                                                  int ni, int ldA) {
  const int tpr = ni >> 3;                      // threads per row (32 or 64)
  const int r = blockIdx.x * (256 / tpr) + threadIdx.x / tpr;
  const int c = (threadIdx.x % tpr) * 8;
  const int s0 = ofs[r], s1 = ofs[r + 1];
  float A0[8], A1[8], A2[8], A3[8];
#pragma unroll
  for (int j = 0; j < 8; ++j) { A0[j] = 0.f; A1[j] = 0.f; A2[j] = 0.f; A3[j] = 0.f; }
  for (int i = s0; i < s1; ++i) {
    const unsigned ad = adj[i];
    const int src = ad & 0x3FFF, t = ad >> 14;
    int4 u = *(const int4*)&y[(long)src * ni + c];
    const ushort* us = (const ushort*)&u;
    if (t == 0) {
#pragma unroll
      for (int j = 0; j < 8; ++j) A0[j] += bf2f(us[j]);
    } else if (t == 1) {
#pragma unroll
      for (int j = 0; j < 8; ++j) A1[j] += bf2f(us[j]);
    } else if (t == 2) {
#pragma unroll
      for (int j = 0; j < 8; ++j) A2[j] += bf2f(us[j]);
    } else {
#pragma unroll
      for (int j = 0; j < 8; ++j) A3[j] += bf2f(us[j]);
    }
  }
  ushort* d = &Abuf[(long)r * ldA + c];
  int4 o; ushort* os = (ushort*)&o;
#pragma unroll
  for (int j = 0; j < 8; ++j) os[j] = f2bf(A0[j]);
  *(int4*)&d[0] = o;
#pragma unroll
  for (int j = 0; j < 8; ++j) os[j] = f2bf(A1[j]);
  *(int4*)&d[ni] = o;
#pragma unroll
  for (int j = 0; j < 8; ++j) os[j] = f2bf(A2[j]);
  *(int4*)&d[2 * ni] = o;
#pragma unroll
  for (int j = 0; j < 8; ++j) os[j] = f2bf(A3[j]);
  *(int4*)&d[3 * ni] = o;
}

// merged: rel scores + index copies (one dispatch, nt stores)
__global__ void erelic_k(const float* Gbuf, const int* ei, const int* et,
                         const float* bg, float* outR, float* oEI, float* oET) {
  const long nrel = (long)E_T * 7;
  long idx = (long)blockIdx.x * 256 + threadIdx.x;
  if (idx < nrel) {
    int e = (int)(idx / 7), r = (int)(idx - (long)e * 7);
    nt_store1(&outR[idx],
              Gbuf[(long)ei[e] * 16 + r] + Gbuf[(long)ei[E_T + e] * 16 + 7 + r] + bg[r]);
  } else {
    long j = idx - nrel;
    if (j < 2 * E_T) nt_store1(&oEI[j], (float)ei[j]);
    else if (j < 3 * E_T) nt_store1(&oET[j - 2 * E_T], (float)et[j - 2 * E_T]);
  }
}

// ---------------- host side ----------------
static GemmP mkp(const ushort* A, long sA, int lda,
                 const ushort* Bt, long sBt, int ldb,
                 int M, int N, int K,
                 float* outF, long sOF, int ldoF,
                 ushort* outB, long sOB, int ldoB,
                 const float* addC, long sC, int ldC,
                 const float* bias, float scale, int relu,
                 int expf_, const float* rowScale, long sRS) {
  GemmP p{};
  p.A = A; p.Bt = Bt; p.outF = outF; p.outB = outB; p.outF2 = nullptr; p.outB2 = nullptr;
  p.addC = addC; p.bias = bias; p.rowScale = rowScale;
  p.sA = sA; p.sBt = sBt; p.sOutF = sOF; p.sOutB = sOB; p.sAddC = sC; p.sRS = sRS;
  p.lda = lda; p.ldb = ldb; p.ldoF = ldoF; p.ldoB = ldoB; p.ldoF2 = 0; p.ldoB2 = 0; p.ldC = ldC;
  p.M = M; p.N = N; p.K = K; p.nSplit = 1 << 30;
  p.scale = scale; p.relu = relu; p.expf_ = expf_;
  return p;
}

static void gemm128(hipStream_t st, const GemmP& p, int Z) {
  dim3 grid(p.M / 128, p.N / 128, Z);
  hipLaunchKernelGGL(gemm_k<128>, grid, dim3(256), 0, st, p);
}
static void gemm64(hipStream_t st, const GemmP& p, int Z) {
  dim3 grid(p.M / 128, p.N / 64, Z);
  hipLaunchKernelGGL(gemm_k<64>, grid, dim3(256), 0, st, p);
}

extern "C" void kernel_launch(void* const* d_in, const int* in_sizes, int n_in,
                              void* d_out_, int out_size, void* d_ws, size_t ws_size,
                              hipStream_t stream) {
  const float* x     = (const float*)d_in[0];
  const int*   tgt_y = (const int*)d_in[1];
  const int*   ei    = (const int*)d_in[2];
  const int*   et    = (const int*)d_in[3];
  const float* emb   = (const float*)d_in[6];
  const float* Wz    = (const float*)d_in[7];
  const float* bz    = (const float*)d_in[8];
  const float* Wg    = (const float*)d_in[9];
  const float* bg    = (const float*)d_in[10];
  const float* We[3] = {(const float*)d_in[11], (const float*)d_in[15], (const float*)d_in[19]};
  const float* Wq[3] = {(const float*)d_in[12], (const float*)d_in[16], (const float*)d_in[20]};
  const float* Wc[3] = {(const float*)d_in[13], (const float*)d_in[17], (const float*)d_in[21]};
  const float* bb[3] = {(const float*)d_in[14], (const float*)d_in[18], (const float*)d_in[22]};
  float* out = (float*)d_out_;

  // ---- workspace layout (ushort units) ----
  ushort* wsu    = (ushort*)d_ws;
  ushort* WzG    = wsu + 0;          // [640][256]: Wz 0-511, Wg1T 512-518, Wg2T 519-525, pad->639
  ushort* WzQ1   = wsu + 163840;     // [768][256]: Wz 0-511, Wq1T 512-767
  ushort* WB0    = wsu + 360448;     // [512][1280]
  ushort* WB1    = wsu + 1015808;    // [512][2304]
  ushort* WB2    = wsu + 2195456;    // [256][2304]
  ushort* WqT2   = wsu + 2785280;    // [256][512]
  ushort* WqT3   = wsu + 2916352;    // [256][512]
  ushort* xb     = wsu + 3047424;    // bf16 x [32768,256]
  ushort* xTb    = wsu + 11436032;   // bf16 xT [32][256][1024]
  ushort* qbuf   = wsu + 19824640;   // bf16 q [16384,256]
  ushort* ybuf   = wsu + 24018944;   // bf16 y [16384,<=512]
  ushort* Abuf   = wsu + 32407552;   // bf16 [16384][<=2304]
  ushort* scoreb = wsu + 70156288;   // bf16 exp-scores [16384,1024]
  float*  Gbuf   = (float*)(wsu + 86933504);  // f32 [16384,16]
  float*  inv    = (float*)(wsu + 91127808);  // 16384 f
  float*  bcat   = (float*)(wsu + 91160576);  // 768 f
  int*    cnt    = (int*)(wsu + 91162112);    // 16384
  int*    ofs    = (int*)(wsu + 91194880);    // 16385
  int*    cur    = (int*)(wsu + 91227712);    // 16384
  ushort* adj    = wsu + 91260480;            // 65536

  ushort* GgT  = WzG + 512 * 256;
  ushort* Wq1T = WzQ1 + 512 * 256;
  ushort* WB[3]  = {WB0, WB1, WB2};
  const int ni_l[3] = {256, 512, 512}, no_l[3] = {512, 512, 256};
  const int ldA_l[3] = {1280, 2304, 2304};

  // ---- small prep ----
  (void)hipMemcpyAsync(bcat, bz, 512 * sizeof(float), hipMemcpyDeviceToDevice, stream);
  (void)hipMemsetAsync(bcat + 512, 0, 256 * sizeof(float), stream);
  (void)hipMemsetAsync(GgT + 14 * 256, 0, (128 - 14) * 256 * sizeof(ushort), stream);
  (void)hipMemsetAsync(cnt, 0, 16384 * sizeof(int), stream);

  // ---- weight transposes (22 slabs, LDS-tiled) ----
  TDs td; int di = 0;
  td.d[di++] = {Wz, WzG, 256, 512, 256};
  td.d[di++] = {Wz, WzQ1, 256, 512, 256};
  td.d[di++] = {Wg, GgT, 256, 7, 256};
  td.d[di++] = {Wg + 256 * 7, GgT + 7 * 256, 256, 7, 256};
  td.d[di++] = {Wq[0], Wq1T, 256, 256, 256};
  for (int l = 0; l < 3; ++l) {
    const int ni = ni_l[l], no = no_l[l], ldA = ldA_l[l];
    for (int t = 0; t < 4; ++t)
      td.d[di++] = {We[l] + (long)t * ni * no, WB[l] + (long)t * ni, ni, no, ldA};
    td.d[di++] = {Wc[l], WB[l] + (long)4 * ni, 256, no, ldA};
    if (l > 0) td.d[di++] = {Wq[l], (l == 1) ? WqT2 : WqT3, ni, 256, ni};
  }
  hipLaunchKernelGGL(t32_k, dim3(16, 16, 22), dim3(256), 0, stream, td);

  hipLaunchKernelGGL(prepx_k, dim3(32, 8, 32), dim3(256), 0, stream, x, xb, xTb);
  hipLaunchKernelGGL(gather_k, dim3(4096), dim3(256), 0, stream, emb, tgt_y, ybuf);

  // ---- CSR build ----
  hipLaunchKernelGGL(deg_k, dim3(256), dim3(256), 0, stream, ei, cnt);
  hipLaunchKernelGGL(scan_k, dim3(1), dim3(256), 0, stream, cnt, ofs, cur);
  hipLaunchKernelGGL(fill_k, dim3(256), dim3(256), 0, stream, ei, et, cur, adj);

  // ---- merged: [embeds_out | q1] = y0 @ [Wz | Wq1]  (BN=128) ----
  {
    GemmP p = mkp(ybuf, 0, 256, WzQ1, 0, 256, NY_T, 768, 256,
                  out + O_EMB, 0, 512, nullptr, 0, 0,
                  nullptr, 0, 0, bcat, 1.0f, 0, 0, nullptr, 0);
    p.nSplit = 512; p.outB2 = qbuf; p.ldoB2 = 256;
    gemm128(stream, p, 1);
  }

  float* alphaO[3] = {out + O_A1, out + O_A2, out + O_A3};
  ushort* WqTn[3] = {nullptr, WqT2, WqT3};

  for (int l = 0; l < 3; ++l) {
    const int ni = ni_l[l], no = no_l[l], ldA = ldA_l[l];
    if (l > 0) {   // q = y @ Wq (BN=64: 512 blocks, 2/CU)
      GemmP p = mkp(ybuf, 0, ni, WqTn[l], 0, ni, NY_T, 256, ni,
                    nullptr, 0, 0, qbuf, 0, 256,
                    nullptr, 0, 0, nullptr, 1.0f, 0, 0, nullptr, 0);
      gemm64(stream, p, 1);
    }
    // ya: CSR gather of y into Abuf[:, 0..4ni)
    hipLaunchKernelGGL(gather_y_k, dim3(NY_T / (256 / (ni >> 3))), dim3(256), 0, stream,
                       ybuf, adj, ofs, Abuf, ni, ldA);
    // e = exp(q @ x^T / 16) (batched, BN=128) -> scoreb bf16
    {
      GemmP p = mkp(qbuf, (long)512 * 256, 256, xb, (long)1024 * 256, 256,
                    512, 1024, 256, nullptr, 0, 0, scoreb, (long)512 * 1024, 1024,
                    nullptr, 0, 0, nullptr, 0.0625f, 0, 1, nullptr, 0);
      gemm128(stream, p, 32);
    }
    // row sums: alpha f32 (nt) -> out, inv -> ws
    hipLaunchKernelGGL(rowsum_k, dim3(8192), dim3(256), 0, stream, scoreb, alphaO[l], inv);
    // ctx = (e @ x) * inv[row] (batched, BN=64: 2 blocks/CU) -> Abuf[:, 4ni..)
    {
      GemmP p = mkp(scoreb, (long)512 * 1024, 1024, xTb, (long)256 * 1024, 1024,
                    512, 256, 1024, nullptr, 0, 0, Abuf + 4 * ni, (long)512 * ldA, ldA,
                    nullptr, 0, 0, nullptr, 1.0f, 0, 0, inv, 512);
      gemm64(stream, p, 32);
    }
    // y_next = relu([ya|ctx] @ WB^T + b)  (BN=128 for N=512, BN=64 for N=256)
    {
      GemmP p = mkp(Abuf, 0, ldA, WB[l], 0, ldA, NY_T, no, ldA,
                    (l == 2) ? out + O_Y3 : nullptr, 0, no, ybuf, 0, no,
                    nullptr, 0, 0, bb[l], 1.0f, 1, 0, nullptr, 0);
      if (no == 256) gemm64(stream, p, 1); else gemm128(stream, p, 1);
    }
  }

  // ---- merged: [y_score | G] = y3 @ [Wz | Wg1 | Wg2 | pad]  (BN=128) ----
  {
    GemmP p = mkp(ybuf, 0, 256, WzG, 0, 256, NY_T, 640, 256,
                  out + O_YS, 0, 512, nullptr, 0, 0,
                  nullptr, 0, 0, bcat, 1.0f, 0, 0, nullptr, 0);
    p.nSplit = 512; p.outF2 = Gbuf; p.ldoF2 = 16;
    gemm128(stream, p, 1);
  }
  hipLaunchKernelGGL(erelic_k, dim3(2560), dim3(256), 0, stream,
                     Gbuf, ei, et, bg, out + O_REL, out + O_EI, out + O_ET);
}